// Round 3
// baseline (3119.374 us; speedup 1.0000x reference)
//
#include <hip/hip_runtime.h>
#include <math.h>

// ---------- problem constants ----------
constexpr int SEQ_T = 72;
constexpr int FDIM  = 64;
constexpr int UNITS = 256;
constexpr int U4    = 1024;
constexpr int KTOT  = 320;     // FDIM + UNITS
constexpr int NKC   = 10;      // z k-chunks of 32
constexpr int NKD   = 8;       // dense k-chunks of 32 (K=256)
constexpr int BATCH = 4096;
constexpr int APITCH = 328;    // LDS row pitch in shorts (656B -> 2-way banks, free)

using short8 = __attribute__((ext_vector_type(8))) short;
using f32x4  = __attribute__((ext_vector_type(4))) float;

__device__ __forceinline__ float sigmoid_fast(float x) {
    return 1.0f / (1.0f + __expf(-x));
}
__device__ __forceinline__ float tanh_fast(float x) {
    float ax = fabsf(x);
    float e  = __expf(2.0f * ax);
    float t  = 1.0f - 2.0f / (e + 1.0f);
    return copysignf(t, x);
}
__device__ __forceinline__ unsigned short f2bf(float f) {
    union { float f; unsigned u; } v; v.f = f;
    unsigned r = (v.u + 0x7FFFu + ((v.u >> 16) & 1u)) >> 16;   // RNE
    return (unsigned short)r;
}

// ---------- prep: Wt[col][k] bf16 ----------
__global__ void prep_wt(const float* __restrict__ W, const float* __restrict__ U,
                        unsigned short* __restrict__ Wt) {
    int k = blockIdx.x;               // 0..319
    #pragma unroll
    for (int i = 0; i < 4; ++i) {
        int col = i * 256 + threadIdx.x;
        float v = (k < FDIM) ? W[(size_t)k * U4 + col] : U[(size_t)(k - FDIM) * U4 + col];
        Wt[(size_t)col * KTOT + k] = f2bf(v);
    }
}

// ---------- prep: Wdt[f][u] bf16 from Wd[u][f] ----------
__global__ void prep_wdt(const float* __restrict__ Wd, unsigned short* __restrict__ Wdt) {
    int f = blockIdx.x;               // 0..63
    int u = threadIdx.x;              // 0..255
    Wdt[(size_t)f * UNITS + u] = f2bf(Wd[(size_t)u * FDIM + f]);
}

// ---------- persistent LSTM kernel ----------
// grid 256 x 256 threads. blk = bx + 64*by; bx = batch tile (64 rows), by = unit tile (64 units).
// Group {bx, bx+64, bx+128, bx+192} -> same XCD (stride 64 preserves blk%8).
// Weights register-resident; c register-resident; h exchanged via double-buffered global.
__global__ __launch_bounds__(256, 1) void lstm_persistent(
    const float* __restrict__ inputs,          // [B][72][64] fp32
    const float* __restrict__ bias,            // [1024] fp32
    const unsigned short* __restrict__ Wt,     // [1024][320] bf16
    const unsigned short* __restrict__ Wdt,    // [64][256] bf16
    const float* __restrict__ bdv,             // [64] fp32
    unsigned short* __restrict__ hbuf,         // [2][B][256] bf16
    unsigned int* __restrict__ flags,          // [64] zeroed per launch
    float* __restrict__ out,                   // [B][out_steps][64] fp32
    int out_steps, int nsteps)                 // nsteps = SEQ_T + out_steps - 1 = 95
{
    const int blk = blockIdx.x;
    const int bx = blk & 63, by = blk >> 6;
    const int bb = bx * 64;                    // batch base
    const int ub = by * 64;                    // unit base
    const int tid = threadIdx.x;
    const int lane = tid & 63;
    const int wu = tid >> 6;                   // wave id = unit-16 tile
    const int l16 = lane & 15, hi4 = lane >> 4;
    const int ulane = ub + wu * 16 + l16;      // this lane's unit column

    __shared__ unsigned short A[64][APITCH];   // [row][k] bf16: x in [0,64), h in [64,320)

    // ---- stationary weights -> registers (once) ----
    short8 Bz[4][NKC];                         // z weights: [gate][kchunk]
    #pragma unroll
    for (int g = 0; g < 4; ++g)
        #pragma unroll
        for (int kc = 0; kc < NKC; ++kc)
            Bz[g][kc] = *reinterpret_cast<const short8*>(
                Wt + (size_t)(g * UNITS + ulane) * KTOT + kc * 32 + hi4 * 8);
    short8 Bd[NKD];                            // dense weights, col f = wu*16+l16
    #pragma unroll
    for (int kc = 0; kc < NKD; ++kc)
        Bd[kc] = *reinterpret_cast<const short8*>(
            Wdt + (size_t)(wu * 16 + l16) * UNITS + kc * 32 + hi4 * 8);

    const float bi_ = bias[0 * UNITS + ulane];
    const float bf_ = bias[1 * UNITS + ulane];
    const float bg_ = bias[2 * UNITS + ulane];
    const float bo_ = bias[3 * UNITS + ulane];
    const float bd_ = bdv[wu * 16 + l16];

    float c_reg[4][4];                         // c state, register-resident all steps
    #pragma unroll
    for (int m = 0; m < 4; ++m)
        #pragma unroll
        for (int j = 0; j < 4; ++j) c_reg[m][j] = 0.0f;

    const int srow = tid >> 2;                 // staging: row 0..63
    const int sseg = tid & 3;                  // staging: quarter-row

    for (int t = 0; t <= nsteps; ++t) {        // t == nsteps: final pred only
        const int cur = t & 1;

        // ---- stage h-part of A from hbuf[cur] (128B contiguous per thread) ----
        {
            const unsigned short* src =
                hbuf + ((size_t)cur * BATCH + bb + srow) * UNITS + sseg * 64;
            #pragma unroll
            for (int i = 0; i < 8; ++i)
                *reinterpret_cast<short8*>(&A[srow][64 + sseg * 64 + i * 8]) =
                    *reinterpret_cast<const short8*>(src + i * 8);
        }

        if (t < SEQ_T) {
            // ---- x from inputs[:, t, :] (fp32 -> bf16) ----
            const float* src = inputs + ((size_t)(bb + srow) * SEQ_T + t) * FDIM + sseg * 16;
            float4 v0 = *reinterpret_cast<const float4*>(src);
            float4 v1 = *reinterpret_cast<const float4*>(src + 4);
            float4 v2 = *reinterpret_cast<const float4*>(src + 8);
            float4 v3 = *reinterpret_cast<const float4*>(src + 12);
            short8 p0, p1;
            p0[0]=(short)f2bf(v0.x); p0[1]=(short)f2bf(v0.y); p0[2]=(short)f2bf(v0.z); p0[3]=(short)f2bf(v0.w);
            p0[4]=(short)f2bf(v1.x); p0[5]=(short)f2bf(v1.y); p0[6]=(short)f2bf(v1.z); p0[7]=(short)f2bf(v1.w);
            p1[0]=(short)f2bf(v2.x); p1[1]=(short)f2bf(v2.y); p1[2]=(short)f2bf(v2.z); p1[3]=(short)f2bf(v2.w);
            p1[4]=(short)f2bf(v3.x); p1[5]=(short)f2bf(v3.y); p1[6]=(short)f2bf(v3.z); p1[7]=(short)f2bf(v3.w);
            *reinterpret_cast<short8*>(&A[srow][sseg * 16])     = p0;
            *reinterpret_cast<short8*>(&A[srow][sseg * 16 + 8]) = p1;
            __syncthreads();
        } else {
            __syncthreads();                   // h-part staged
            // ---- pred = h @ Wd + bd (dense head, fused) ----
            f32x4 accp[4];
            #pragma unroll
            for (int m = 0; m < 4; ++m) accp[m] = (f32x4){0.f, 0.f, 0.f, 0.f};
            #pragma unroll
            for (int kc = 0; kc < NKD; ++kc) {
                #pragma unroll
                for (int m = 0; m < 4; ++m) {
                    short8 a = *reinterpret_cast<const short8*>(
                        &A[m * 16 + l16][64 + kc * 32 + hi4 * 8]);
                    accp[m] = __builtin_amdgcn_mfma_f32_16x16x32_bf16(a, Bd[kc], accp[m], 0, 0, 0);
                }
            }
            const int s = t - SEQ_T;           // pred_s
            const int f = wu * 16 + l16;
            #pragma unroll
            for (int m = 0; m < 4; ++m) {
                #pragma unroll
                for (int j = 0; j < 4; ++j) {
                    float v = accp[m][j] + bd_;
                    int row = m * 16 + hi4 * 4 + j;
                    A[row][f] = f2bf(v);       // x for next LSTM step
                    if (by == 0)
                        out[(size_t)(bb + row) * (out_steps * FDIM) + (size_t)s * FDIM + f] = v;
                }
            }
            __syncthreads();                   // x writes visible to z-MFMA
        }

        if (t == nsteps) break;                // final pred done

        // ---- z = [x|h] @ [W;U] : 160 MFMAs/wave, weights from registers ----
        f32x4 acc[4][4];                       // [m][gate]
        #pragma unroll
        for (int m = 0; m < 4; ++m)
            #pragma unroll
            for (int g = 0; g < 4; ++g) acc[m][g] = (f32x4){0.f, 0.f, 0.f, 0.f};
        #pragma unroll
        for (int kc = 0; kc < NKC; ++kc) {
            short8 a[4];
            #pragma unroll
            for (int m = 0; m < 4; ++m)
                a[m] = *reinterpret_cast<const short8*>(&A[m * 16 + l16][kc * 32 + hi4 * 8]);
            #pragma unroll
            for (int m = 0; m < 4; ++m)
                #pragma unroll
                for (int g = 0; g < 4; ++g)
                    acc[m][g] = __builtin_amdgcn_mfma_f32_16x16x32_bf16(a[m], Bz[g][kc], acc[m][g], 0, 0, 0);
        }

        // ---- gates + state update; h_{t+1} -> hbuf[1-cur] ----
        unsigned short* hdst = hbuf + (size_t)(1 - cur) * BATCH * UNITS;
        #pragma unroll
        for (int m = 0; m < 4; ++m) {
            #pragma unroll
            for (int j = 0; j < 4; ++j) {
                float zi = acc[m][0][j] + bi_;
                float zf = acc[m][1][j] + bf_;
                float zg = acc[m][2][j] + bg_;
                float zo = acc[m][3][j] + bo_;
                float ig = sigmoid_fast(zi);
                float fg = sigmoid_fast(zf);
                float og = sigmoid_fast(zo);
                float cn = fg * c_reg[m][j] + ig * tanh_fast(zg);
                c_reg[m][j] = cn;
                float hv = og * tanh_fast(cn);
                int row = bb + m * 16 + hi4 * 4 + j;
                hdst[(size_t)row * UNITS + ulane] = f2bf(hv);
            }
        }

        // ---- 4-block group barrier (device-scope atomics, same-XCD group) ----
        __syncthreads();                       // drains each wave's stores (vmcnt0 before s_barrier)
        if (tid == 0)
            __hip_atomic_fetch_add(&flags[bx], 1u, __ATOMIC_RELEASE, __HIP_MEMORY_SCOPE_AGENT);
        if (lane == 0) {
            const unsigned target = 4u * (unsigned)(t + 1);
            while (__hip_atomic_load(&flags[bx], __ATOMIC_ACQUIRE, __HIP_MEMORY_SCOPE_AGENT) < target)
                __builtin_amdgcn_s_sleep(4);
        }
        __syncthreads();
    }
}

extern "C" void kernel_launch(void* const* d_in, const int* in_sizes, int n_in,
                              void* d_out, int out_size, void* d_ws, size_t ws_size,
                              hipStream_t stream) {
    const float* inputs = (const float*)d_in[0];
    const float* W      = (const float*)d_in[1];
    const float* U      = (const float*)d_in[2];
    const float* b      = (const float*)d_in[3];
    const float* Wd     = (const float*)d_in[4];
    const float* bd     = (const float*)d_in[5];
    float* out = (float*)d_out;

    const int out_steps = out_size / (BATCH * FDIM);   // 24
    const int nsteps = SEQ_T + out_steps - 1;          // 95

    // ---- workspace carve ----
    char* ws = (char*)d_ws;
    unsigned short* hbuf  = (unsigned short*)(ws);              // 2*4096*256*2 = 4 MB
    unsigned int*   flags = (unsigned int*)(ws + (4u << 20));   // 256 B (4 KB reserved)
    unsigned short* Wt    = (unsigned short*)(ws + (5u << 20)); // 640 KB
    unsigned short* Wdt   = (unsigned short*)(ws + (6u << 20)); // 32 KB

    prep_wt<<<KTOT, 256, 0, stream>>>(W, U, Wt);
    prep_wdt<<<FDIM, 256, 0, stream>>>(Wd, Wdt);
    hipMemsetAsync(hbuf,  0, (size_t)BATCH * UNITS * sizeof(unsigned short), stream); // hbuf[0]
    hipMemsetAsync(flags, 0, 64 * sizeof(unsigned int), stream);

    lstm_persistent<<<dim3(256), dim3(256), 0, stream>>>(
        inputs, b, Wt, Wdt, bd, hbuf, flags, out, out_steps, nsteps);
}

// Round 4
// 2416.648 us; speedup vs baseline: 1.2908x; 1.2908x over previous
//
#include <hip/hip_runtime.h>
#include <math.h>
#include <stdint.h>

// ---------- problem constants ----------
constexpr int SEQ_T  = 72;
constexpr int FDIM   = 64;
constexpr int UNITS  = 256;
constexpr int U4     = 1024;
constexpr int KTOT   = 320;    // FDIM + UNITS
constexpr int BATCH  = 4096;
constexpr int APITCH = 328;    // A row pitch in shorts (656 B, 16B-aligned)
constexpr int WDP    = 264;    // Wdt LDS pitch in shorts (528 B, 16B-aligned)

// LDS layout (dynamic, bytes)
constexpr int OFF_A    = 0;                    // 16 x 328 x 2 = 10496
constexpr int OFF_WDT  = 10496;                // 64 x 264 x 2 = 33792
constexpr int OFF_SLOT = 44288;                // 64 KB stream slot
constexpr int LDS_BYTES = 44288 + 65536;       // 109824 <= 128 KiB

using bf16x8 = __attribute__((ext_vector_type(8))) short;
using bf16x4 = __attribute__((ext_vector_type(4))) short;
using f32x4  = __attribute__((ext_vector_type(4))) float;

__device__ __forceinline__ float sigmoid_fast(float x) {
    return 1.0f / (1.0f + __expf(-x));
}
__device__ __forceinline__ float tanh_fast(float x) {
    float ax = fabsf(x);
    float e  = __expf(2.0f * ax);
    float t  = 1.0f - 2.0f / (e + 1.0f);
    return copysignf(t, x);
}
__device__ __forceinline__ unsigned short f2bf(float f) {
    union { float f; unsigned u; } v; v.f = f;
    unsigned r = (v.u + 0x7FFFu + ((v.u >> 16) & 1u)) >> 16;   // RNE
    return (unsigned short)r;
}

// ---------- prep: Wt[col][k] bf16 (col 0..1023, k 0..319) ----------
__global__ void prep_wt(const float* __restrict__ W, const float* __restrict__ U,
                        unsigned short* __restrict__ Wt) {
    int k = blockIdx.x;               // 0..319
    #pragma unroll
    for (int i = 0; i < 4; ++i) {
        int col = i * 256 + threadIdx.x;
        float v = (k < FDIM) ? W[(size_t)k * U4 + col] : U[(size_t)(k - FDIM) * U4 + col];
        Wt[(size_t)col * KTOT + k] = f2bf(v);
    }
}

// ---------- prep: Wdt[f][u] bf16 from Wd[u][f] ----------
__global__ void prep_wdt(const float* __restrict__ Wd, unsigned short* __restrict__ Wdt) {
    int f = blockIdx.x;               // 0..63
    int u = threadIdx.x;              // 0..255
    Wdt[(size_t)f * UNITS + u] = f2bf(Wd[(size_t)u * FDIM + f]);
}

// async global->LDS 16B, per-lane global src, wave-uniform LDS base + lane*16
__device__ __forceinline__ void gload16_lds(const unsigned short* g, char* l) {
    __builtin_amdgcn_global_load_lds(
        (const __attribute__((address_space(1))) void*)g,
        (__attribute__((address_space(3))) void*)l, 16, 0, 0);
}

// ---------- persistent, fully block-local LSTM ----------
// grid 256 x 512 threads. Block owns batch rows [blk*16, blk*16+16), ALL 1024 z-cols.
// Weights: kc 0-4 VGPR-static per wave; kc 5-9 streamed L2->LDS slot each step;
// Wdt + A-tile ([x|h] 16 x 320) in LDS. h, c, pred never leave the block.
__global__ __launch_bounds__(512, 2) void lstm_persistent(
    const float* __restrict__ inputs,          // [B][72][64] fp32
    const float* __restrict__ bias,            // [1024] fp32
    const unsigned short* __restrict__ Wt,     // [1024][320] bf16
    const unsigned short* __restrict__ Wdt,    // [64][256] bf16
    const float* __restrict__ bd,              // [64] fp32
    float* __restrict__ out,                   // [B][out_steps][64] fp32
    int out_steps)
{
    extern __shared__ char smem[];
    unsigned short* A_s  = (unsigned short*)(smem + OFF_A);
    unsigned short* WdtL = (unsigned short*)(smem + OFF_WDT);
    char*           slot = smem + OFF_SLOT;

    const int tid  = threadIdx.x;
    const int w    = tid >> 6;                 // wave 0..7
    const int lane = tid & 63;
    const int l16  = lane & 15, hi4 = lane >> 4;
    const int w32  = w * 32;                   // wave's unit base
    const int bb   = blockIdx.x * 16;          // batch base (16 rows)

    // ---- init: zero h-region of A ----
    {
        int idx = tid * 8;                     // 4096 shorts total
        int r = idx >> 8, cc = idx & 255;
        bf16x8 z8 = {0,0,0,0,0,0,0,0};
        *(bf16x8*)(A_s + r * APITCH + 64 + cc) = z8;
    }
    // ---- init: Wdt -> LDS (padded pitch) ----
    {
        int f = tid >> 3, seg = tid & 7;
        #pragma unroll
        for (int q = 0; q < 4; ++q)
            *(bf16x8*)(WdtL + f * WDP + seg * 32 + q * 8) =
                *(const bf16x8*)(Wdt + (size_t)f * UNITS + seg * 32 + q * 8);
    }
    // ---- init: static weight fragments kc 0..4 -> VGPR (160 regs/lane) ----
    bf16x8 Breg[5][4][2];
    #pragma unroll
    for (int kc = 0; kc < 5; ++kc)
        #pragma unroll
        for (int g = 0; g < 4; ++g)
            #pragma unroll
            for (int ut = 0; ut < 2; ++ut)
                Breg[kc][g][ut] = *(const bf16x8*)(
                    Wt + (size_t)(g * 256 + w32 + ut * 16 + l16) * KTOT + kc * 32 + hi4 * 8);

    // ---- biases ----
    float bz[4][2];
    #pragma unroll
    for (int g = 0; g < 4; ++g)
        #pragma unroll
        for (int ut = 0; ut < 2; ++ut)
            bz[g][ut] = bias[g * 256 + w32 + ut * 16 + l16];
    const float bdv = (w < 4) ? bd[w * 16 + l16] : 0.0f;

    float c_reg[2][4];
    #pragma unroll
    for (int ut = 0; ut < 2; ++ut)
        #pragma unroll
        for (int j = 0; j < 4; ++j) c_reg[ut][j] = 0.0f;

    // streaming source base: this lane's column within each half
    const unsigned short* gp0 = Wt + (size_t)(w * 64 + lane) * KTOT;
    char* slotw = slot + w * 1024;             // wave's landing base within a half

    const unsigned short* Aw = A_s + l16 * APITCH + hi4 * 8;   // a-frag base
    const int tmax = SEQ_T + out_steps - 1;    // 95

    __syncthreads();

    #pragma unroll 1
    for (int t = 0; t <= tmax; ++t) {
        // ================= input staging / dense head =================
        if (t < SEQ_T) {
            if (tid < 256) {                   // 16 rows x 16 float4
                int r = tid >> 4, c4 = tid & 15;
                float4 v = *reinterpret_cast<const float4*>(
                    inputs + ((size_t)(bb + r) * SEQ_T + t) * FDIM + c4 * 4);
                bf16x4 p;
                p[0] = (short)f2bf(v.x); p[1] = (short)f2bf(v.y);
                p[2] = (short)f2bf(v.z); p[3] = (short)f2bf(v.w);
                *(bf16x4*)(A_s + r * APITCH + c4 * 4) = p;
            }
        } else {
            // pred = h @ Wd + bd : waves 0-3 each own a 16-col f-tile
            if (w < 4) {
                const int f = w * 16 + l16;
                f32x4 accp = {0.f, 0.f, 0.f, 0.f};
                #pragma unroll
                for (int kc = 0; kc < 8; ++kc) {
                    bf16x8 a = *(const bf16x8*)(Aw + 64 + kc * 32);
                    bf16x8 bfr = *(const bf16x8*)(WdtL + f * WDP + kc * 32 + hi4 * 8);
                    accp = __builtin_amdgcn_mfma_f32_16x16x32_bf16(a, bfr, accp, 0, 0, 0);
                }
                const int s = t - SEQ_T;
                #pragma unroll
                for (int j = 0; j < 4; ++j) {
                    int r = hi4 * 4 + j;
                    float v = accp[j] + bdv;
                    out[((size_t)(bb + r) * out_steps + s) * FDIM + f] = v;
                    A_s[r * APITCH + f] = f2bf(v);     // feedback as next x
                }
            }
        }
        __syncthreads();                       // B1: A fully staged
        if (t == tmax) break;

        // ================= z = [x|h] @ [W;U] =================
        // issue stream kc5 (both halves) -> 8 loads in flight
        #pragma unroll
        for (int j = 0; j < 4; ++j)
            gload16_lds(gp0 + 160 + j * 8, slotw + j * 8192);
        #pragma unroll
        for (int j = 0; j < 4; ++j)
            gload16_lds(gp0 + (size_t)512 * KTOT + 160 + j * 8, slotw + 32768 + j * 8192);

        f32x4 acc[4][2];
        #pragma unroll
        for (int g = 0; g < 4; ++g)
            #pragma unroll
            for (int ut = 0; ut < 2; ++ut) acc[g][ut] = (f32x4){0.f, 0.f, 0.f, 0.f};

        // static part (kc 0-4) runs under the stream loads
        #pragma unroll
        for (int kc = 0; kc < 5; ++kc) {
            bf16x8 a = *(const bf16x8*)(Aw + kc * 32);
            #pragma unroll
            for (int g = 0; g < 4; ++g)
                #pragma unroll
                for (int ut = 0; ut < 2; ++ut)
                    acc[g][ut] = __builtin_amdgcn_mfma_f32_16x16x32_bf16(
                        a, Breg[kc][g][ut], acc[g][ut], 0, 0, 0);
        }

        // streamed part (kc 5-9), column-half pipelined
        #pragma unroll
        for (int k = 5; k <= 9; ++k) {
            asm volatile("s_waitcnt vmcnt(4)" ::: "memory");   // own H0 landed
            __builtin_amdgcn_s_barrier();                      // all waves' H0 landed
            __builtin_amdgcn_sched_barrier(0);
            bf16x8 a = *(const bf16x8*)(Aw + k * 32);
            #pragma unroll
            for (int g = 0; g < 2; ++g)                        // H0: gates 0,1
                #pragma unroll
                for (int ut = 0; ut < 2; ++ut) {
                    bf16x8 bfr = *(const bf16x8*)(
                        slot + hi4 * 8192 + (g * 256 + w32 + ut * 16 + l16) * 16);
                    acc[g][ut] = __builtin_amdgcn_mfma_f32_16x16x32_bf16(
                        a, bfr, acc[g][ut], 0, 0, 0);
                }
            asm volatile("s_waitcnt vmcnt(0)" ::: "memory");   // H1 landed
            __builtin_amdgcn_s_barrier();                      // + all done with H0
            __builtin_amdgcn_sched_barrier(0);
            if (k < 9) {
                #pragma unroll
                for (int j = 0; j < 4; ++j)
                    gload16_lds(gp0 + 160 + (k + 1 - 5) * 32 + j * 8, slotw + j * 8192);
            }
            #pragma unroll
            for (int g = 2; g < 4; ++g)                        // H1: gates 2,3
                #pragma unroll
                for (int ut = 0; ut < 2; ++ut) {
                    bf16x8 bfr = *(const bf16x8*)(
                        slot + 32768 + hi4 * 8192 + ((g - 2) * 256 + w32 + ut * 16 + l16) * 16);
                    acc[g][ut] = __builtin_amdgcn_mfma_f32_16x16x32_bf16(
                        a, bfr, acc[g][ut], 0, 0, 0);
                }
            __builtin_amdgcn_s_barrier();                      // all done with H1
            __builtin_amdgcn_sched_barrier(0);
            if (k < 9) {
                #pragma unroll
                for (int j = 0; j < 4; ++j)
                    gload16_lds(gp0 + (size_t)512 * KTOT + 160 + (k + 1 - 5) * 32 + j * 8,
                                slotw + 32768 + j * 8192);
            }
        }

        // ================= gates + state update, h -> A (LDS only) =================
        #pragma unroll
        for (int ut = 0; ut < 2; ++ut) {
            #pragma unroll
            for (int j = 0; j < 4; ++j) {
                float zi = acc[0][ut][j] + bz[0][ut];
                float zf = acc[1][ut][j] + bz[1][ut];
                float zg = acc[2][ut][j] + bz[2][ut];
                float zo = acc[3][ut][j] + bz[3][ut];
                float ig = sigmoid_fast(zi);
                float fg = sigmoid_fast(zf);
                float og = sigmoid_fast(zo);
                float cn = fg * c_reg[ut][j] + ig * tanh_fast(zg);
                c_reg[ut][j] = cn;
                int r = hi4 * 4 + j;
                A_s[r * APITCH + 64 + w32 + ut * 16 + l16] = f2bf(og * tanh_fast(cn));
            }
        }
        __syncthreads();                       // B0: h_{t+1} visible; slot idle
    }
}

extern "C" void kernel_launch(void* const* d_in, const int* in_sizes, int n_in,
                              void* d_out, int out_size, void* d_ws, size_t ws_size,
                              hipStream_t stream) {
    const float* inputs = (const float*)d_in[0];
    const float* W      = (const float*)d_in[1];
    const float* U      = (const float*)d_in[2];
    const float* b      = (const float*)d_in[3];
    const float* Wd     = (const float*)d_in[4];
    const float* bd     = (const float*)d_in[5];
    float* out = (float*)d_out;

    const int out_steps = out_size / (BATCH * FDIM);   // 24

    // ---- workspace carve ----
    char* ws = (char*)d_ws;
    unsigned short* Wt  = (unsigned short*)(ws);                 // 640 KB
    unsigned short* Wdt = (unsigned short*)(ws + (1u << 20));    // 32 KB

    prep_wt<<<KTOT, 256, 0, stream>>>(W, U, Wt);
    prep_wdt<<<FDIM, 256, 0, stream>>>(Wd, Wdt);

    (void)hipFuncSetAttribute((const void*)lstm_persistent,
                              hipFuncAttributeMaxDynamicSharedMemorySize, LDS_BYTES);

    lstm_persistent<<<dim3(BATCH / 16), dim3(512), LDS_BYTES, stream>>>(
        inputs, b, Wt, Wdt, bd, out, out_steps);
}

// Round 6
// 1246.169 us; speedup vs baseline: 2.5032x; 1.9393x over previous
//
#include <hip/hip_runtime.h>
#include <math.h>

// ---------- problem constants ----------
constexpr int SEQ_T = 72;
constexpr int FDIM  = 64;
constexpr int UNITS = 256;
constexpr int U4    = 1024;
constexpr int KTOT  = 320;   // FDIM + UNITS (10 k-chunks of 32)
constexpr int BATCH = 4096;
constexpr int NSTREAM = 6;   // streamed kc 4..9

// LDS layout (dynamic, bytes). hb: h fragment blobs, 2 parities x 8 KB.
// xb: decode x rows, 2 parities x 16x68 f32. ring: 8 waves x 2 slots x 8 KB.
constexpr int OFF_HB   = 0;
constexpr int OFF_XB   = 16384;
constexpr int XB_PITCH = 68;                    // f32, 272 B rows (16B aligned)
constexpr int OFF_RING = 16384 + 2 * 16 * XB_PITCH * 4;   // 25088
constexpr int LDS_BYTES = 25088 + 8 * 2 * 8192;           // 156160

using bf16x8 = __attribute__((ext_vector_type(8))) short;
using f32x4  = __attribute__((ext_vector_type(4))) float;

__device__ __forceinline__ float sigmoid_fast(float x) {
    return 1.0f / (1.0f + __expf(-x));
}
__device__ __forceinline__ float tanh_fast(float x) {
    float ax = fabsf(x);
    float e  = __expf(2.0f * ax);
    float t  = 1.0f - 2.0f / (e + 1.0f);
    return copysignf(t, x);
}
__device__ __forceinline__ unsigned short f2bf(float f) {
    union { float f; unsigned u; } v; v.f = f;
    unsigned r = (v.u + 0x7FFFu + ((v.u >> 16) & 1u)) >> 16;   // RNE
    return (unsigned short)r;
}
__device__ __forceinline__ bf16x8 pack8(float4 a, float4 b) {
    bf16x8 p;
    p[0] = (short)f2bf(a.x); p[1] = (short)f2bf(a.y);
    p[2] = (short)f2bf(a.z); p[3] = (short)f2bf(a.w);
    p[4] = (short)f2bf(b.x); p[5] = (short)f2bf(b.y);
    p[6] = (short)f2bf(b.z); p[7] = (short)f2bf(b.w);
    return p;
}

// ---------- prep: z-weights as MFMA B-fragment blobs ----------
// blob lane idx = ((w*10 + kc)*8 + ct)*64 + l, 8 bf16 each.
// col = (ct>>1)*256 + w*32 + (ct&1)*16 + (l&15); k = kc*32 + (l>>4)*8 + e.
__global__ void prep_wblob(const float* __restrict__ W, const float* __restrict__ U,
                           unsigned short* __restrict__ Wblob) {
    int id = blockIdx.x * 256 + threadIdx.x;    // 40960
    int l  = id & 63;
    int ct = (id >> 6) & 7;
    int wk = id >> 9;                           // w*10 + kc
    int kc = wk % 10, w = wk / 10;
    int col = (ct >> 1) * 256 + w * 32 + (ct & 1) * 16 + (l & 15);
    int kb  = kc * 32 + (l >> 4) * 8;
    bf16x8 v;
    #pragma unroll
    for (int e = 0; e < 8; ++e) {
        int k = kb + e;
        float f = (k < FDIM) ? W[(size_t)k * U4 + col] : U[(size_t)(k - FDIM) * U4 + col];
        v[e] = (short)f2bf(f);
    }
    *reinterpret_cast<bf16x8*>(Wblob + (size_t)id * 8) = v;
}

// ---------- prep: dense weights as B-fragment blobs ----------
// blob idx = (w*8 + kcd)*64 + l ; f = w*16 + (l&15); k = kcd*32 + (l>>4)*8 + e.
__global__ void prep_wdblob(const float* __restrict__ Wd, unsigned short* __restrict__ Wdblob) {
    int id = blockIdx.x * 256 + threadIdx.x;    // 2048
    int l   = id & 63;
    int kcd = (id >> 6) & 7;
    int w   = id >> 9;
    int f   = w * 16 + (l & 15);
    int kb  = kcd * 32 + (l >> 4) * 8;
    bf16x8 v;
    #pragma unroll
    for (int e = 0; e < 8; ++e)
        v[e] = (short)f2bf(Wd[(size_t)(kb + e) * FDIM + f]);
    *reinterpret_cast<bf16x8*>(Wdblob + (size_t)id * 8) = v;
}

__device__ __forceinline__ void gload16_lds(const unsigned short* g, char* l) {
    __builtin_amdgcn_global_load_lds(
        (const __attribute__((address_space(1))) void*)g,
        (__attribute__((address_space(3))) void*)l, 16, 0, 0);
}

// ---------- persistent, fully block-local LSTM ----------
// grid 256 x 512 (8 waves). Block owns 16 batch rows, ALL 1024 z-cols.
// Wave w owns units [w*32, w*32+32) x 4 gates = 8 col-tiles.
// kc0..3 weights VGPR-static; kc4..9 streamed L2->private LDS ring (counted vmcnt,
// no barriers). h double-buffered in LDS by step parity -> race-free.
__global__ __launch_bounds__(512, 2) void lstm_persistent(
    const float* __restrict__ inputs,          // [B][72][64] fp32
    const float* __restrict__ bias,            // [1024] fp32
    const unsigned short* __restrict__ Wblob,  // frag-ordered z-weights (640 KB)
    const unsigned short* __restrict__ Wdblob, // frag-ordered dense weights (32 KB)
    const float* __restrict__ bd,              // [64] fp32
    float* __restrict__ out,                   // [B][out_steps][64] fp32
    int out_steps)
{
    extern __shared__ char smem[];
    unsigned short* hb = (unsigned short*)(smem + OFF_HB);   // [2][4096] shorts
    float*          xb = (float*)(smem + OFF_XB);            // [2][16*68] f32
    char*         ring = smem + OFF_RING;

    const int tid = threadIdx.x;
    const int w = tid >> 6, lane = tid & 63;
    const int l16 = lane & 15, hi4 = lane >> 4;
    const int bb = blockIdx.x * 16;
    char* ringw = ring + w * 16384;

    // zero h blob parity 0 (8192 B, 16 B/thread)
    *reinterpret_cast<bf16x8*>(hb + tid * 8) = (bf16x8){0, 0, 0, 0, 0, 0, 0, 0};

    // ---- static weight fragments kc 0..3 (W kc0,1 + U kc2,3): 128 VGPRs ----
    bf16x8 Bs[4][8];
    #pragma unroll
    for (int kc = 0; kc < 4; ++kc)
        #pragma unroll
        for (int ct = 0; ct < 8; ++ct)
            Bs[kc][ct] = *reinterpret_cast<const bf16x8*>(
                Wblob + (size_t)(((w * 10 + kc) * 8 + ct) * 64 + lane) * 8);

    float bz[4][2];
    #pragma unroll
    for (int g = 0; g < 4; ++g)
        #pragma unroll
        for (int ut = 0; ut < 2; ++ut)
            bz[g][ut] = bias[g * 256 + w * 32 + ut * 16 + l16];
    const float bdv = bd[(w & 3) * 16 + l16];

    float c_reg[2][4];
    #pragma unroll
    for (int ut = 0; ut < 2; ++ut)
        #pragma unroll
        for (int j = 0; j < 4; ++j) c_reg[ut][j] = 0.0f;

    const int tmax = SEQ_T + out_steps - 1;    // 95

    #pragma unroll 1
    for (int t = 0; ; ++t) {
        const int p = t & 1;

        // ================ dense head (decode steps) ================
        if (t >= SEQ_T) {
            __syncthreads();                   // B0: h_t visible in hb[p]
            if (w < 4) {
                f32x4 accp = {0.f, 0.f, 0.f, 0.f};
                #pragma unroll
                for (int kcd = 0; kcd < 8; ++kcd) {
                    bf16x8 a = *reinterpret_cast<const bf16x8*>(
                        hb + p * 4096 + (kcd * 64 + lane) * 8);
                    bf16x8 bw = *reinterpret_cast<const bf16x8*>(
                        Wdblob + (size_t)(((w * 8 + kcd) * 64) + lane) * 8);
                    accp = __builtin_amdgcn_mfma_f32_16x16x32_bf16(a, bw, accp, 0, 0, 0);
                }
                const int s = t - SEQ_T;
                const int f = w * 16 + l16;
                #pragma unroll
                for (int j = 0; j < 4; ++j) {
                    int r = hi4 * 4 + j;
                    float v = accp[j] + bdv;
                    out[((size_t)(bb + r) * out_steps + s) * FDIM + f] = v;
                    xb[p * (16 * XB_PITCH) + r * XB_PITCH + f] = v;   // feedback x_t
                }
            }
        }
        if (t == tmax) break;
        __syncthreads();                       // B1: hb[p] + x source ready

        // ================ z phase ================
        // warmup x loads first (oldest vmem ops -> transparent to chunk counts)
        float4 x0a, x0b, x1a, x1b;
        if (t < SEQ_T) {
            const float* xr = inputs + ((size_t)(bb + l16) * SEQ_T + t) * FDIM + hi4 * 8;
            x0a = *reinterpret_cast<const float4*>(xr);
            x0b = *reinterpret_cast<const float4*>(xr + 4);
            x1a = *reinterpret_cast<const float4*>(xr + 32);
            x1b = *reinterpret_cast<const float4*>(xr + 36);
        }

        // issue chunks c0,c1 (kc 4,5) into ring slots 0,1
        #pragma unroll
        for (int c = 0; c < 2; ++c)
            #pragma unroll
            for (int ct = 0; ct < 8; ++ct)
                gload16_lds(Wblob + (size_t)(((w * 10 + 4 + c) * 8 + ct) * 64 + lane) * 8,
                            ringw + (c & 1) * 8192 + ct * 1024);

        f32x4 acc[8];
        #pragma unroll
        for (int ct = 0; ct < 8; ++ct) acc[ct] = (f32x4){0.f, 0.f, 0.f, 0.f};

        // static U part: kc 2,3
        #pragma unroll
        for (int kc = 2; kc < 4; ++kc) {
            bf16x8 a = *reinterpret_cast<const bf16x8*>(
                hb + p * 4096 + ((kc - 2) * 64 + lane) * 8);
            #pragma unroll
            for (int ct = 0; ct < 8; ++ct)
                acc[ct] = __builtin_amdgcn_mfma_f32_16x16x32_bf16(a, Bs[kc][ct], acc[ct], 0, 0, 0);
        }

        // streamed chunks c0..c4 (kc 4..8), 2-deep ring, counted vmcnt
        #pragma unroll
        for (int c = 0; c < 5; ++c) {
            asm volatile("s_waitcnt vmcnt(8)" ::: "memory");
            char* sl = ringw + (c & 1) * 8192;
            bf16x8 a = *reinterpret_cast<const bf16x8*>(
                hb + p * 4096 + ((c + 2) * 64 + lane) * 8);
            #pragma unroll
            for (int ct = 0; ct < 8; ++ct) {
                bf16x8 bfr = *reinterpret_cast<const bf16x8*>(sl + ct * 1024 + lane * 16);
                acc[ct] = __builtin_amdgcn_mfma_f32_16x16x32_bf16(a, bfr, acc[ct], 0, 0, 0);
            }
            if (c + 2 < NSTREAM) {
                #pragma unroll
                for (int ct = 0; ct < 8; ++ct)
                    gload16_lds(Wblob + (size_t)(((w * 10 + 4 + c + 2) * 8 + ct) * 64 + lane) * 8,
                                ringw + (c & 1) * 8192 + ct * 1024);
            }
        }

        // x part: kc 0,1 (hidden under the stream)
        bf16x8 ax0, ax1;
        if (t < SEQ_T) {
            ax0 = pack8(x0a, x0b);
            ax1 = pack8(x1a, x1b);
        } else {
            const float* xr = xb + p * (16 * XB_PITCH) + l16 * XB_PITCH + hi4 * 8;
            ax0 = pack8(*reinterpret_cast<const float4*>(xr),
                        *reinterpret_cast<const float4*>(xr + 4));
            ax1 = pack8(*reinterpret_cast<const float4*>(xr + 32),
                        *reinterpret_cast<const float4*>(xr + 36));
        }
        #pragma unroll
        for (int ct = 0; ct < 8; ++ct)
            acc[ct] = __builtin_amdgcn_mfma_f32_16x16x32_bf16(ax0, Bs[0][ct], acc[ct], 0, 0, 0);
        #pragma unroll
        for (int ct = 0; ct < 8; ++ct)
            acc[ct] = __builtin_amdgcn_mfma_f32_16x16x32_bf16(ax1, Bs[1][ct], acc[ct], 0, 0, 0);

        // last chunk c5 (kc 9)
        asm volatile("s_waitcnt vmcnt(0)" ::: "memory");
        {
            char* sl = ringw + 8192;           // slot 1
            bf16x8 a = *reinterpret_cast<const bf16x8*>(
                hb + p * 4096 + (7 * 64 + lane) * 8);
            #pragma unroll
            for (int ct = 0; ct < 8; ++ct) {
                bf16x8 bfr = *reinterpret_cast<const bf16x8*>(sl + ct * 1024 + lane * 16);
                acc[ct] = __builtin_amdgcn_mfma_f32_16x16x32_bf16(a, bfr, acc[ct], 0, 0, 0);
            }
        }

        // ================ gates + state update; h_{t+1} -> hb[1-p] ================
        #pragma unroll
        for (int ut = 0; ut < 2; ++ut) {
            #pragma unroll
            for (int j = 0; j < 4; ++j) {
                float zi = acc[0 + ut][j] + bz[0][ut];
                float zf = acc[2 + ut][j] + bz[1][ut];
                float zg = acc[4 + ut][j] + bz[2][ut];
                float zo = acc[6 + ut][j] + bz[3][ut];
                float ig = sigmoid_fast(zi);
                float fg = sigmoid_fast(zf);
                float og = sigmoid_fast(zo);
                float cn = fg * c_reg[ut][j] + ig * tanh_fast(zg);
                c_reg[ut][j] = cn;
                float hv = og * tanh_fast(cn);
                int r  = hi4 * 4 + j;
                int lp = (ut * 2 + (l16 >> 3)) * 16 + r;
                hb[(1 - p) * 4096 + w * 512 + lp * 8 + (l16 & 7)] = f2bf(hv);
            }
        }
    }
}

extern "C" void kernel_launch(void* const* d_in, const int* in_sizes, int n_in,
                              void* d_out, int out_size, void* d_ws, size_t ws_size,
                              hipStream_t stream) {
    const float* inputs = (const float*)d_in[0];
    const float* W      = (const float*)d_in[1];
    const float* U      = (const float*)d_in[2];
    const float* b      = (const float*)d_in[3];
    const float* Wd     = (const float*)d_in[4];
    const float* bd     = (const float*)d_in[5];
    float* out = (float*)d_out;

    const int out_steps = out_size / (BATCH * FDIM);   // 24

    char* ws = (char*)d_ws;
    unsigned short* Wblob  = (unsigned short*)(ws);               // 640 KB
    unsigned short* Wdblob = (unsigned short*)(ws + (1u << 20));  // 32 KB

    prep_wblob<<<160, 256, 0, stream>>>(W, U, Wblob);
    prep_wdblob<<<8, 256, 0, stream>>>(Wd, Wdblob);

    (void)hipFuncSetAttribute((const void*)lstm_persistent,
                              hipFuncAttributeMaxDynamicSharedMemorySize, LDS_BYTES);

    lstm_persistent<<<dim3(BATCH / 16), dim3(512), LDS_BYTES, stream>>>(
        inputs, b, Wblob, Wdblob, bd, out, out_steps);
}

// Round 7
// 872.732 us; speedup vs baseline: 3.5743x; 1.4279x over previous
//
#include <hip/hip_runtime.h>
#include <math.h>

// ---------- problem constants ----------
constexpr int SEQ_T = 72;
constexpr int FDIM  = 64;
constexpr int UNITS = 256;
constexpr int U4    = 1024;
constexpr int KTOT  = 320;   // FDIM + UNITS (10 k-chunks of 32)
constexpr int BATCH = 4096;

// LDS layout (dynamic, bytes)
constexpr int OFF_HB   = 0;                    // 2 parities x 8192 B (h frag blobs)
constexpr int OFF_XB   = 16384;                // 2 x 16 x 68 f32 = 8704 B
constexpr int XB_PITCH = 68;
constexpr int OFF_WL   = 25088;                // 2 kc x 64 KB weight cache
constexpr int LDS_BYTES = 25088 + 131072;      // 156160 <= 160 KiB

using bf16x8 = __attribute__((ext_vector_type(8))) short;
using f32x4  = __attribute__((ext_vector_type(4))) float;

__device__ __forceinline__ float sigmoid_fast(float x) {
    return 1.0f / (1.0f + __expf(-x));
}
__device__ __forceinline__ float tanh_fast(float x) {
    float ax = fabsf(x);
    float e  = __expf(2.0f * ax);
    float t  = 1.0f - 2.0f / (e + 1.0f);
    return copysignf(t, x);
}
__device__ __forceinline__ unsigned short f2bf(float f) {
    union { float f; unsigned u; } v; v.f = f;
    unsigned r = (v.u + 0x7FFFu + ((v.u >> 16) & 1u)) >> 16;   // RNE
    return (unsigned short)r;
}
__device__ __forceinline__ bf16x8 pack8(float4 a, float4 b) {
    bf16x8 p;
    p[0] = (short)f2bf(a.x); p[1] = (short)f2bf(a.y);
    p[2] = (short)f2bf(a.z); p[3] = (short)f2bf(a.w);
    p[4] = (short)f2bf(b.x); p[5] = (short)f2bf(b.y);
    p[6] = (short)f2bf(b.z); p[7] = (short)f2bf(b.w);
    return p;
}

// ---------- prep: z-weights as MFMA B-fragment blobs ----------
// blob idx = ((w*10 + kc)*8 + ct)*64 + l, 8 bf16 each.
// col = (ct>>1)*256 + w*32 + (ct&1)*16 + (l&15); k = kc*32 + (l>>4)*8 + e.
__global__ void prep_wblob(const float* __restrict__ W, const float* __restrict__ U,
                           unsigned short* __restrict__ Wblob) {
    int id = blockIdx.x * 256 + threadIdx.x;    // 40960
    int l  = id & 63;
    int ct = (id >> 6) & 7;
    int wk = id >> 9;                           // w*10 + kc
    int kc = wk % 10, w = wk / 10;
    int col = (ct >> 1) * 256 + w * 32 + (ct & 1) * 16 + (l & 15);
    int kb  = kc * 32 + (l >> 4) * 8;
    bf16x8 v;
    #pragma unroll
    for (int e = 0; e < 8; ++e) {
        int k = kb + e;
        float f = (k < FDIM) ? W[(size_t)k * U4 + col] : U[(size_t)(k - FDIM) * U4 + col];
        v[e] = (short)f2bf(f);
    }
    *reinterpret_cast<bf16x8*>(Wblob + (size_t)id * 8) = v;
}

// ---------- prep: dense weights as B-fragment blobs ----------
__global__ void prep_wdblob(const float* __restrict__ Wd, unsigned short* __restrict__ Wdblob) {
    int id = blockIdx.x * 256 + threadIdx.x;    // 2048
    int l   = id & 63;
    int kcd = (id >> 6) & 7;
    int w   = id >> 9;
    int f   = w * 16 + (l & 15);
    int kb  = kcd * 32 + (l >> 4) * 8;
    bf16x8 v;
    #pragma unroll
    for (int e = 0; e < 8; ++e)
        v[e] = (short)f2bf(Wd[(size_t)(kb + e) * FDIM + f]);
    *reinterpret_cast<bf16x8*>(Wdblob + (size_t)id * 8) = v;
}

// ---------- persistent, fully block-local LSTM ----------
// grid 256 x 512 (8 waves, amdgpu_waves_per_eu(2,2) -> 256-VGPR budget).
// Block owns 16 batch rows, ALL 1024 z-cols; wave w owns units [w*32,w*32+32) x 4 gates.
// Weights: kc0-3 VGPR-static (128 regs); kc4,5 LDS-cached once (128 KB);
// kc6-9 streamed from L2 via plain coalesced loads (compiler-scheduled waits).
// h double-buffered in LDS by parity; h/c/pred never leave the block.
__global__ void __launch_bounds__(512)
__attribute__((amdgpu_waves_per_eu(2, 2)))
lstm_persistent(
    const float* __restrict__ inputs,          // [B][72][64] fp32
    const float* __restrict__ bias,            // [1024] fp32
    const unsigned short* __restrict__ Wblob,  // frag-ordered z-weights (640 KB)
    const unsigned short* __restrict__ Wdblob, // frag-ordered dense weights (32 KB)
    const float* __restrict__ bd,              // [64] fp32
    float* __restrict__ out,                   // [B][out_steps][64] fp32
    int out_steps)
{
    extern __shared__ char smem[];
    unsigned short* hb = (unsigned short*)(smem + OFF_HB);   // [2][4096] shorts
    float*          xb = (float*)(smem + OFF_XB);            // [2][16*68] f32
    char*           WL = smem + OFF_WL;                      // [2][8][8][64][16B]

    const int tid = threadIdx.x;
    const int w = tid >> 6, lane = tid & 63;
    const int l16 = lane & 15, hi4 = lane >> 4;
    const int bb = blockIdx.x * 16;

    auto blob = [&](int kc, int ct) -> const bf16x8* {
        return reinterpret_cast<const bf16x8*>(
            Wblob + (size_t)(((w * 10 + kc) * 8 + ct) * 64 + lane) * 8);
    };

    // zero h blob parity 0 (8192 B, 16 B/thread)
    *reinterpret_cast<bf16x8*>(hb + tid * 8) = (bf16x8){0, 0, 0, 0, 0, 0, 0, 0};

    // ---- LDS weight cache: kc4,5 (own wave's slice) ----
    #pragma unroll
    for (int i = 0; i < 2; ++i)
        #pragma unroll
        for (int ct = 0; ct < 8; ++ct)
            *reinterpret_cast<bf16x8*>(WL + (i * 8 + w) * 8192 + ct * 1024 + lane * 16) =
                *blob(4 + i, ct);

    // ---- static weight fragments kc0-3 (W kc0,1 + U kc2,3): 128 VGPRs ----
    bf16x8 Bs[4][8];
    #pragma unroll
    for (int kc = 0; kc < 4; ++kc)
        #pragma unroll
        for (int ct = 0; ct < 8; ++ct)
            Bs[kc][ct] = *blob(kc, ct);

    float bz[4][2];
    #pragma unroll
    for (int g = 0; g < 4; ++g)
        #pragma unroll
        for (int ut = 0; ut < 2; ++ut)
            bz[g][ut] = bias[g * 256 + w * 32 + ut * 16 + l16];
    const float bdv = bd[(w & 3) * 16 + l16];

    float c_reg[2][4];
    #pragma unroll
    for (int ut = 0; ut < 2; ++ut)
        #pragma unroll
        for (int j = 0; j < 4; ++j) c_reg[ut][j] = 0.0f;

    const int tmax = SEQ_T + out_steps - 1;    // 95

    #pragma unroll 1
    for (int t = 0; ; ++t) {
        const int p = t & 1;

        // ================ dense head (decode steps) ================
        if (t >= SEQ_T) {
            __syncthreads();                   // B0: h_t visible in hb[p]
            if (w < 4) {
                f32x4 accp = {0.f, 0.f, 0.f, 0.f};
                #pragma unroll
                for (int kcd = 0; kcd < 8; ++kcd) {
                    bf16x8 a = *reinterpret_cast<const bf16x8*>(
                        hb + p * 4096 + (kcd * 64 + lane) * 8);
                    bf16x8 bw = *reinterpret_cast<const bf16x8*>(
                        Wdblob + (size_t)(((w * 8 + kcd) * 64) + lane) * 8);
                    accp = __builtin_amdgcn_mfma_f32_16x16x32_bf16(a, bw, accp, 0, 0, 0);
                }
                const int s = t - SEQ_T;
                const int f = w * 16 + l16;
                #pragma unroll
                for (int j = 0; j < 4; ++j) {
                    int r = hi4 * 4 + j;
                    float v = accp[j] + bdv;
                    out[((size_t)(bb + r) * out_steps + s) * FDIM + f] = v;
                    xb[p * (16 * XB_PITCH) + r * XB_PITCH + f] = v;   // feedback x_t
                }
            }
        }
        if (t == tmax) break;
        __syncthreads();                       // B1: hb[p] + x source ready

        // ================ z = [x|h] @ [W;U] ================
        // stream kc6,7 (issued first; consumed after statics/LDS chunks)
        bf16x8 s6[8], s7[8], s8[8], s9[8];
        #pragma unroll
        for (int ct = 0; ct < 8; ++ct) s6[ct] = *blob(6, ct);
        #pragma unroll
        for (int ct = 0; ct < 8; ++ct) s7[ct] = *blob(7, ct);

        // x A-frags
        bf16x8 ax0, ax1;
        if (t < SEQ_T) {
            const float* xr = inputs + ((size_t)(bb + l16) * SEQ_T + t) * FDIM + hi4 * 8;
            ax0 = pack8(*reinterpret_cast<const float4*>(xr),
                        *reinterpret_cast<const float4*>(xr + 4));
            ax1 = pack8(*reinterpret_cast<const float4*>(xr + 32),
                        *reinterpret_cast<const float4*>(xr + 36));
        } else {
            const float* xr = xb + p * (16 * XB_PITCH) + l16 * XB_PITCH + hi4 * 8;
            ax0 = pack8(*reinterpret_cast<const float4*>(xr),
                        *reinterpret_cast<const float4*>(xr + 4));
            ax1 = pack8(*reinterpret_cast<const float4*>(xr + 32),
                        *reinterpret_cast<const float4*>(xr + 36));
        }

        f32x4 acc[8];
        #pragma unroll
        for (int ct = 0; ct < 8; ++ct) acc[ct] = (f32x4){0.f, 0.f, 0.f, 0.f};

        // kc0,1: x part (statics)
        #pragma unroll
        for (int ct = 0; ct < 8; ++ct)
            acc[ct] = __builtin_amdgcn_mfma_f32_16x16x32_bf16(ax0, Bs[0][ct], acc[ct], 0, 0, 0);
        #pragma unroll
        for (int ct = 0; ct < 8; ++ct)
            acc[ct] = __builtin_amdgcn_mfma_f32_16x16x32_bf16(ax1, Bs[1][ct], acc[ct], 0, 0, 0);

        // kc2,3: h part (statics)
        #pragma unroll
        for (int kc = 2; kc < 4; ++kc) {
            bf16x8 a = *reinterpret_cast<const bf16x8*>(
                hb + p * 4096 + ((kc - 2) * 64 + lane) * 8);
            #pragma unroll
            for (int ct = 0; ct < 8; ++ct)
                acc[ct] = __builtin_amdgcn_mfma_f32_16x16x32_bf16(a, Bs[kc][ct], acc[ct], 0, 0, 0);
        }

        // kc4,5: h part (LDS weight cache)
        #pragma unroll
        for (int i = 0; i < 2; ++i) {
            bf16x8 a = *reinterpret_cast<const bf16x8*>(
                hb + p * 4096 + ((2 + i) * 64 + lane) * 8);
            #pragma unroll
            for (int ct = 0; ct < 8; ++ct) {
                bf16x8 bw = *reinterpret_cast<const bf16x8*>(
                    WL + (i * 8 + w) * 8192 + ct * 1024 + lane * 16);
                acc[ct] = __builtin_amdgcn_mfma_f32_16x16x32_bf16(a, bw, acc[ct], 0, 0, 0);
            }
        }

        // kc6: consume s6, issue s8
        {
            bf16x8 a = *reinterpret_cast<const bf16x8*>(hb + p * 4096 + (4 * 64 + lane) * 8);
            #pragma unroll
            for (int ct = 0; ct < 8; ++ct)
                acc[ct] = __builtin_amdgcn_mfma_f32_16x16x32_bf16(a, s6[ct], acc[ct], 0, 0, 0);
            #pragma unroll
            for (int ct = 0; ct < 8; ++ct) s8[ct] = *blob(8, ct);
        }
        // kc7: consume s7, issue s9
        {
            bf16x8 a = *reinterpret_cast<const bf16x8*>(hb + p * 4096 + (5 * 64 + lane) * 8);
            #pragma unroll
            for (int ct = 0; ct < 8; ++ct)
                acc[ct] = __builtin_amdgcn_mfma_f32_16x16x32_bf16(a, s7[ct], acc[ct], 0, 0, 0);
            #pragma unroll
            for (int ct = 0; ct < 8; ++ct) s9[ct] = *blob(9, ct);
        }
        // kc8, kc9
        {
            bf16x8 a = *reinterpret_cast<const bf16x8*>(hb + p * 4096 + (6 * 64 + lane) * 8);
            #pragma unroll
            for (int ct = 0; ct < 8; ++ct)
                acc[ct] = __builtin_amdgcn_mfma_f32_16x16x32_bf16(a, s8[ct], acc[ct], 0, 0, 0);
        }
        {
            bf16x8 a = *reinterpret_cast<const bf16x8*>(hb + p * 4096 + (7 * 64 + lane) * 8);
            #pragma unroll
            for (int ct = 0; ct < 8; ++ct)
                acc[ct] = __builtin_amdgcn_mfma_f32_16x16x32_bf16(a, s9[ct], acc[ct], 0, 0, 0);
        }

        // ================ gates + state update; h_{t+1} -> hb[1-p] ================
        #pragma unroll
        for (int ut = 0; ut < 2; ++ut) {
            #pragma unroll
            for (int j = 0; j < 4; ++j) {
                float zi = acc[0 + ut][j] + bz[0][ut];
                float zf = acc[2 + ut][j] + bz[1][ut];
                float zg = acc[4 + ut][j] + bz[2][ut];
                float zo = acc[6 + ut][j] + bz[3][ut];
                float ig = sigmoid_fast(zi);
                float fg = sigmoid_fast(zf);
                float og = sigmoid_fast(zo);
                float cn = fg * c_reg[ut][j] + ig * tanh_fast(zg);
                c_reg[ut][j] = cn;
                float hv = og * tanh_fast(cn);
                int r  = hi4 * 4 + j;
                int lp = (ut * 2 + (l16 >> 3)) * 16 + r;
                hb[(1 - p) * 4096 + w * 512 + lp * 8 + (l16 & 7)] = f2bf(hv);
            }
        }
    }
}

extern "C" void kernel_launch(void* const* d_in, const int* in_sizes, int n_in,
                              void* d_out, int out_size, void* d_ws, size_t ws_size,
                              hipStream_t stream) {
    const float* inputs = (const float*)d_in[0];
    const float* W      = (const float*)d_in[1];
    const float* U      = (const float*)d_in[2];
    const float* b      = (const float*)d_in[3];
    const float* Wd     = (const float*)d_in[4];
    const float* bd     = (const float*)d_in[5];
    float* out = (float*)d_out;

    const int out_steps = out_size / (BATCH * FDIM);   // 24

    char* ws = (char*)d_ws;
    unsigned short* Wblob  = (unsigned short*)(ws);               // 640 KB
    unsigned short* Wdblob = (unsigned short*)(ws + (1u << 20));  // 32 KB

    prep_wblob<<<160, 256, 0, stream>>>(W, U, Wblob);
    prep_wdblob<<<8, 256, 0, stream>>>(Wd, Wdblob);

    (void)hipFuncSetAttribute((const void*)lstm_persistent,
                              hipFuncAttributeMaxDynamicSharedMemorySize, LDS_BYTES);

    lstm_persistent<<<dim3(BATCH / 16), dim3(512), LDS_BYTES, stream>>>(
        inputs, b, Wblob, Wdblob, bd, out, out_steps);
}